// Round 1
// baseline (363.665 us; speedup 1.0000x reference)
//
#include <hip/hip_runtime.h>

#define INCH 128
#define HIDCH 128
#define OUTCH 64

// ---------------- degree histogram ----------------
__global__ __launch_bounds__(256) void k_deg(const int* __restrict__ dst,
                                             int* __restrict__ deg, int e) {
    int i = blockIdx.x * 256 + threadIdx.x;
    if (i < e) atomicAdd(&deg[dst[i]], 1);
}

// ---------------- 3-kernel exclusive scan over deg -> row_start ----------------
__global__ __launch_bounds__(256) void k_block_reduce(const int* __restrict__ deg,
                                                      int* __restrict__ bsum, int n) {
    __shared__ int sm[256];
    int i = blockIdx.x * 256 + threadIdx.x;
    sm[threadIdx.x] = (i < n) ? deg[i] : 0;
    __syncthreads();
    for (int s = 128; s > 0; s >>= 1) {
        if (threadIdx.x < s) sm[threadIdx.x] += sm[threadIdx.x + s];
        __syncthreads();
    }
    if (threadIdx.x == 0) bsum[blockIdx.x] = sm[0];
}

__global__ __launch_bounds__(256) void k_scan_bsum(int* bsum, int nb) {
    // single block, nb <= 256
    __shared__ int sm[256];
    int t = threadIdx.x;
    int v = (t < nb) ? bsum[t] : 0;
    sm[t] = v;
    __syncthreads();
    for (int off = 1; off < 256; off <<= 1) {
        int add = (t >= off) ? sm[t - off] : 0;
        __syncthreads();
        sm[t] += add;
        __syncthreads();
    }
    if (t < nb) bsum[t] = sm[t] - v;  // exclusive
}

__global__ __launch_bounds__(256) void k_scan_final(const int* __restrict__ deg,
                                                    const int* __restrict__ bsum,
                                                    int* __restrict__ row_start, int n) {
    __shared__ int sm[256];
    int t = threadIdx.x;
    int i = blockIdx.x * 256 + t;
    int v = (i < n) ? deg[i] : 0;
    sm[t] = v;
    __syncthreads();
    for (int off = 1; off < 256; off <<= 1) {
        int add = (t >= off) ? sm[t - off] : 0;
        __syncthreads();
        sm[t] += add;
        __syncthreads();
    }
    if (i < n) row_start[i] = bsum[blockIdx.x] + sm[t] - v;
}

// ---------------- CSR fill (atomic cursor per dst) ----------------
__global__ __launch_bounds__(256) void k_fill_csr(const int* __restrict__ src,
                                                  const int* __restrict__ dst,
                                                  const int* __restrict__ row_start,
                                                  int* __restrict__ cursor,
                                                  int* __restrict__ csr_src, int e) {
    int i = blockIdx.x * 256 + threadIdx.x;
    if (i < e) {
        int d = dst[i];
        int pos = atomicAdd(&cursor[d], 1);
        csr_src[row_start[d] + pos] = src[i];
    }
}

// ---------------- fp32 GEMM: C[M x BN] = A[M x 128] @ W[128 x BN] (+bias) ----------------
template <int BN, bool BIAS>
__global__ __launch_bounds__(256) void k_gemm(const float* __restrict__ A,
                                              const float* __restrict__ W,
                                              const float* __restrict__ bias,
                                              float* __restrict__ C, int M) {
    constexpr int CG = BN / 4;    // column groups (each handles 4 cols)
    constexpr int RG = 256 / CG;  // row groups
    constexpr int TM = 64 / RG;   // rows per thread
    __shared__ float As[64][32];
    __shared__ float Ws[32][BN];
    const int m0 = blockIdx.x * 64;
    const int cg = threadIdx.x % CG;
    const int rg = threadIdx.x / CG;
    float4 acc[TM];
#pragma unroll
    for (int i = 0; i < TM; ++i) acc[i] = make_float4(0.f, 0.f, 0.f, 0.f);

    for (int k0 = 0; k0 < 128; k0 += 32) {
        // stage A tile: 64 rows x 32 k  (512 float4)
        for (int q = threadIdx.x; q < 512; q += 256) {
            int row = q >> 3, kq = q & 7;
            float4 v = make_float4(0.f, 0.f, 0.f, 0.f);
            int gr = m0 + row;
            if (gr < M) v = *(const float4*)&A[gr * 128 + k0 + kq * 4];
            *(float4*)&As[row][kq * 4] = v;
        }
        // stage W tile: 32 k x BN  (8*BN float4)
        for (int q = threadIdx.x; q < 8 * BN; q += 256) {
            int k = q / (BN / 4), nq = q % (BN / 4);
            *(float4*)&Ws[k][nq * 4] = *(const float4*)&W[(k0 + k) * BN + nq * 4];
        }
        __syncthreads();
#pragma unroll
        for (int kk = 0; kk < 32; ++kk) {
            float4 w = *(const float4*)&Ws[kk][cg * 4];
#pragma unroll
            for (int i = 0; i < TM; ++i) {
                float a = As[rg * TM + i][kk];
                acc[i].x += a * w.x;
                acc[i].y += a * w.y;
                acc[i].z += a * w.z;
                acc[i].w += a * w.w;
            }
        }
        __syncthreads();
    }

    float4 bv = make_float4(0.f, 0.f, 0.f, 0.f);
    if (BIAS) bv = *(const float4*)&bias[cg * 4];
#pragma unroll
    for (int i = 0; i < TM; ++i) {
        int gr = m0 + rg * TM + i;
        if (gr < M) {
            float4 r = acc[i];
            r.x += bv.x; r.y += bv.y; r.z += bv.z; r.w += bv.w;
            *(float4*)&C[gr * BN + cg * 4] = r;
        }
    }
}

// ---------------- layer-1 aggregation: h = relu(s + mean_neigh(p)) ----------------
// one wave (64 lanes) per node, 2 f32 per lane (128 channels)
__global__ __launch_bounds__(256) void k_agg1_relu(const float* __restrict__ p,
                                                   float* __restrict__ h,
                                                   const int* __restrict__ row_start,
                                                   const int* __restrict__ deg,
                                                   const int* __restrict__ csr_src, int n) {
    int gw = (blockIdx.x * 256 + threadIdx.x) >> 6;
    int lane = threadIdx.x & 63;
    if (gw >= n) return;
    int start = row_start[gw];
    int cnt = deg[gw];
    float sx = 0.f, sy = 0.f;
    for (int i = 0; i < cnt; ++i) {
        int s = csr_src[start + i];
        float2 v = *(const float2*)&p[s * 128 + lane * 2];
        sx += v.x;
        sy += v.y;
    }
    float inv = 1.0f / fmaxf((float)cnt, 1.0f);
    float2 cur = *(const float2*)&h[gw * 128 + lane * 2];
    float2 r;
    r.x = fmaxf(cur.x + inv * sx, 0.f);
    r.y = fmaxf(cur.y + inv * sy, 0.f);
    *(float2*)&h[gw * 128 + lane * 2] = r;
}

// ---------------- layer-2 aggregation: out += mean_neigh(p)  (64 channels) ----------------
__global__ __launch_bounds__(256) void k_agg2_add(const float* __restrict__ p,
                                                  float* __restrict__ out,
                                                  const int* __restrict__ row_start,
                                                  const int* __restrict__ deg,
                                                  const int* __restrict__ csr_src, int n) {
    int gw = (blockIdx.x * 256 + threadIdx.x) >> 6;
    int lane = threadIdx.x & 63;
    if (gw >= n) return;
    int start = row_start[gw];
    int cnt = deg[gw];
    float s = 0.f;
    for (int i = 0; i < cnt; ++i) {
        int e = csr_src[start + i];
        s += p[e * 64 + lane];
    }
    float inv = 1.0f / fmaxf((float)cnt, 1.0f);
    out[gw * 64 + lane] += inv * s;
}

extern "C" void kernel_launch(void* const* d_in, const int* in_sizes, int n_in,
                              void* d_out, int out_size, void* d_ws, size_t ws_size,
                              hipStream_t stream) {
    const float* x   = (const float*)d_in[0];
    const int*   src = (const int*)d_in[1];
    const int*   dst = (const int*)d_in[2];
    const float* Ws1 = (const float*)d_in[3];
    const float* Wn1 = (const float*)d_in[4];
    const float* b1  = (const float*)d_in[5];
    const float* Ws2 = (const float*)d_in[6];
    const float* Wn2 = (const float*)d_in[7];
    const float* b2  = (const float*)d_in[8];
    float* out = (float*)d_out;
    const int N = in_sizes[0] / INCH;  // 50000
    const int E = in_sizes[1];         // 800000

    // workspace layout (all offsets 256B-aligned)
    char* ws = (char*)d_ws;
    int* deg       = (int*)(ws + 0);         // N ints
    int* row_start = (int*)(ws + 200704);    // N ints
    int* cursor    = (int*)(ws + 401408);    // N ints
    int* bsum      = (int*)(ws + 602112);    // ceil(N/256) ints
    int* csr_src   = (int*)(ws + 603136);    // E ints (3.2 MB)
    float* pbuf    = (float*)(ws + 3803136); // N*128 f32 (25.6 MB): p1, then p2
    float* sbuf    = (float*)(ws + 29403136);// N*128 f32 (25.6 MB): s1, then h1 in place

    hipMemsetAsync(deg, 0, N * sizeof(int), stream);
    hipMemsetAsync(cursor, 0, N * sizeof(int), stream);

    const int eb = (E + 255) / 256;
    const int nb = (N + 255) / 256;  // 196 <= 256 (single-block scan OK)
    k_deg<<<eb, 256, 0, stream>>>(dst, deg, E);
    k_block_reduce<<<nb, 256, 0, stream>>>(deg, bsum, N);
    k_scan_bsum<<<1, 256, 0, stream>>>(bsum, nb);
    k_scan_final<<<nb, 256, 0, stream>>>(deg, bsum, row_start, N);
    k_fill_csr<<<eb, 256, 0, stream>>>(src, dst, row_start, cursor, csr_src, E);

    const int gb = (N + 63) / 64;
    // layer 1: s1 = x@W_self1 + b1 ; p1 = x@W_neigh1 ; h1 = relu(s1 + mean(p1))
    k_gemm<128, true><<<gb, 256, 0, stream>>>(x, Ws1, b1, sbuf, N);
    k_gemm<128, false><<<gb, 256, 0, stream>>>(x, Wn1, nullptr, pbuf, N);
    k_agg1_relu<<<(N + 3) / 4, 256, 0, stream>>>(pbuf, sbuf, row_start, deg, csr_src, N);
    // layer 2: p2 = h1@W_neigh2 ; out = h1@W_self2 + b2 ; out += mean(p2)
    k_gemm<64, false><<<gb, 256, 0, stream>>>(sbuf, Wn2, nullptr, pbuf, N);
    k_gemm<64, true><<<gb, 256, 0, stream>>>(sbuf, Ws2, b2, out, N);
    k_agg2_add<<<(N + 3) / 4, 256, 0, stream>>>(pbuf, out, row_start, deg, csr_src, N);
}

// Round 2
// 223.723 us; speedup vs baseline: 1.6255x; 1.6255x over previous
//
#include <hip/hip_runtime.h>

#define N_CH 128

typedef short bf16x8 __attribute__((ext_vector_type(8)));
typedef float f32x4 __attribute__((ext_vector_type(4)));

__device__ __forceinline__ unsigned short f2bf(float f) {
    unsigned int u = __float_as_uint(f);
    unsigned int r = (u + 0x7fffu + ((u >> 16) & 1u)) >> 16;
    return (unsigned short)r;
}
__device__ __forceinline__ unsigned int pkbf(float a, float b) {
    return (unsigned int)f2bf(a) | ((unsigned int)f2bf(b) << 16);
}
__device__ __forceinline__ float bflo(unsigned int v) { return __uint_as_float(v << 16); }
__device__ __forceinline__ float bfhi(unsigned int v) { return __uint_as_float(v & 0xffff0000u); }

// ---------------- degree histogram ----------------
__global__ __launch_bounds__(256) void k_deg(const int* __restrict__ dst,
                                             int* __restrict__ deg, int e) {
    int i = blockIdx.x * 256 + threadIdx.x;
    if (i < e) atomicAdd(&deg[dst[i]], 1);
}

// ---------------- 3-kernel exclusive scan over deg -> row_start ----------------
__global__ __launch_bounds__(256) void k_block_reduce(const int* __restrict__ deg,
                                                      int* __restrict__ bsum, int n) {
    __shared__ int sm[256];
    int i = blockIdx.x * 256 + threadIdx.x;
    sm[threadIdx.x] = (i < n) ? deg[i] : 0;
    __syncthreads();
    for (int s = 128; s > 0; s >>= 1) {
        if (threadIdx.x < s) sm[threadIdx.x] += sm[threadIdx.x + s];
        __syncthreads();
    }
    if (threadIdx.x == 0) bsum[blockIdx.x] = sm[0];
}

__global__ __launch_bounds__(256) void k_scan_bsum(int* bsum, int nb) {
    __shared__ int sm[256];
    int t = threadIdx.x;
    int v = (t < nb) ? bsum[t] : 0;
    sm[t] = v;
    __syncthreads();
    for (int off = 1; off < 256; off <<= 1) {
        int add = (t >= off) ? sm[t - off] : 0;
        __syncthreads();
        sm[t] += add;
        __syncthreads();
    }
    if (t < nb) bsum[t] = sm[t] - v;  // exclusive
}

__global__ __launch_bounds__(256) void k_scan_final(const int* __restrict__ deg,
                                                    const int* __restrict__ bsum,
                                                    int* __restrict__ row_start, int n) {
    __shared__ int sm[256];
    int t = threadIdx.x;
    int i = blockIdx.x * 256 + t;
    int v = (i < n) ? deg[i] : 0;
    sm[t] = v;
    __syncthreads();
    for (int off = 1; off < 256; off <<= 1) {
        int add = (t >= off) ? sm[t - off] : 0;
        __syncthreads();
        sm[t] += add;
        __syncthreads();
    }
    if (i < n) row_start[i] = bsum[blockIdx.x] + sm[t] - v;
}

// ---------------- CSR fill (atomic cursor per dst) ----------------
__global__ __launch_bounds__(256) void k_fill_csr(const int* __restrict__ src,
                                                  const int* __restrict__ dst,
                                                  const int* __restrict__ row_start,
                                                  int* __restrict__ cursor,
                                                  int* __restrict__ csr_src, int e) {
    int i = blockIdx.x * 256 + threadIdx.x;
    if (i < e) {
        int d = dst[i];
        int pos = atomicAdd(&cursor[d], 1);
        csr_src[row_start[d] + pos] = src[i];
    }
}

// ---------------- weight prep: fp32 [K][N] -> bf16 transposed [n][k] ----------------
// Bt1: [256][128] (cols 0..127 = Ws1, 128..255 = Wn1)
// Bt2: [128][128] (cols 0..63 = Ws2, 64..127 = Wn2)
__global__ __launch_bounds__(256) void k_prep(const float* __restrict__ Ws1,
                                              const float* __restrict__ Wn1,
                                              const float* __restrict__ Ws2,
                                              const float* __restrict__ Wn2,
                                              unsigned short* __restrict__ Bt1,
                                              unsigned short* __restrict__ Bt2) {
    int idx = blockIdx.x * 256 + threadIdx.x;
    if (idx < 256 * 128) {
        int n = idx >> 7, k = idx & 127;
        const float* W = (n < 128) ? Ws1 : Wn1;
        Bt1[idx] = f2bf(W[k * 128 + (n & 127)]);
    } else {
        int j = idx - 256 * 128;
        if (j < 128 * 128) {
            int n = j >> 7, k = j & 127;
            const float* W = (n < 64) ? Ws2 : Wn2;
            Bt2[j] = f2bf(W[k * 64 + (n & 63)]);
        }
    }
}

// ---------------- dual MFMA GEMM: [S | P] = A[M x 128] @ [B0 | B1] ----------------
// A: fp32 (AF32) or bf16-ushort [M][128]. Bt: [2NH][128] bf16 n-major.
// S: fp32 [M][NH] = A@B0 + bias ; P: bf16 ushort [M][NH] = A@B1
template <int NH, bool AF32>
__global__ __launch_bounds__(256) void k_gemm_dual(const void* __restrict__ Aptr,
                                                   const unsigned short* __restrict__ Bt,
                                                   const float* __restrict__ bias,
                                                   float* __restrict__ S,
                                                   unsigned short* __restrict__ P, int M) {
    constexpr int TN = 2 * NH;      // total output cols
    constexpr int WC = TN / 4;      // cols per wave
    constexpr int NCT = WC / 16;    // 16-col tiles per wave
    __shared__ unsigned short As[64][128];  // chunk-of-8 XOR swizzled
    __shared__ unsigned short Bs[TN][128];

    const int m0 = blockIdx.x * 64;
    const int tid = threadIdx.x;
    const int w = tid >> 6;
    const int l = tid & 63;

    // stage A (64 rows x 16 chunks of 8 ch), swizzle chunk ^= row&7
    if (AF32) {
        const float* A = (const float*)Aptr;
        for (int q = tid; q < 1024; q += 256) {
            int row = q >> 4, c = q & 15;
            int gr = m0 + row;
            uint4 o = make_uint4(0, 0, 0, 0);
            if (gr < M) {
                float4 f0 = *(const float4*)&A[gr * 128 + c * 8];
                float4 f1 = *(const float4*)&A[gr * 128 + c * 8 + 4];
                o.x = pkbf(f0.x, f0.y); o.y = pkbf(f0.z, f0.w);
                o.z = pkbf(f1.x, f1.y); o.w = pkbf(f1.z, f1.w);
            }
            *(uint4*)&As[row][(c ^ (row & 7)) * 8] = o;
        }
    } else {
        const uint4* A = (const uint4*)Aptr;  // [M][16 chunks]
        for (int q = tid; q < 1024; q += 256) {
            int row = q >> 4, c = q & 15;
            int gr = m0 + row;
            uint4 v = make_uint4(0, 0, 0, 0);
            if (gr < M) v = A[gr * 16 + c];
            *(uint4*)&As[row][(c ^ (row & 7)) * 8] = v;
        }
    }
    // stage B (TN rows x 16 chunks)
    {
        const uint4* B4 = (const uint4*)Bt;
        for (int q = tid; q < TN * 16; q += 256) {
            int n = q >> 4, c = q & 15;
            *(uint4*)&Bs[n][(c ^ (n & 7)) * 8] = B4[n * 16 + c];
        }
    }
    __syncthreads();

    // A fragments: wave computes all 64 rows (4 row-tiles) x its WC cols
    const int fr = l & 15;   // row/col within tile
    const int kq = l >> 4;   // k-quarter (8 consecutive k)
    bf16x8 af[4][4];
#pragma unroll
    for (int rt = 0; rt < 4; ++rt) {
        int row = rt * 16 + fr;
#pragma unroll
        for (int kt = 0; kt < 4; ++kt) {
            int c = (kt * 4 + kq) ^ (row & 7);
            af[rt][kt] = *(bf16x8*)&As[row][c * 8];
        }
    }

    f32x4 acc[NCT][4] = {};
#pragma unroll
    for (int ct = 0; ct < NCT; ++ct) {
        int n = w * WC + ct * 16 + fr;
        bf16x8 bfr[4];
#pragma unroll
        for (int kt = 0; kt < 4; ++kt) {
            int c = (kt * 4 + kq) ^ (n & 7);
            bfr[kt] = *(bf16x8*)&Bs[n][c * 8];
        }
#pragma unroll
        for (int rt = 0; rt < 4; ++rt)
#pragma unroll
            for (int kt = 0; kt < 4; ++kt)
                acc[ct][rt] = __builtin_amdgcn_mfma_f32_16x16x32_bf16(af[rt][kt], bfr[kt],
                                                                      acc[ct][rt], 0, 0, 0);
    }

    // epilogue: C/D layout col = l&15, row = (l>>4)*4 + j
#pragma unroll
    for (int ct = 0; ct < NCT; ++ct) {
        int ncol = w * WC + ct * 16 + fr;
        bool isS = ncol < NH;  // wave-uniform (WC strips)
        float bv = isS ? bias[ncol] : 0.f;
#pragma unroll
        for (int rt = 0; rt < 4; ++rt) {
#pragma unroll
            for (int j = 0; j < 4; ++j) {
                int row = m0 + rt * 16 + (l >> 4) * 4 + j;
                if (row < M) {
                    float v = acc[ct][rt][j];
                    if (isS) S[row * NH + ncol] = v + bv;
                    else P[row * NH + (ncol - NH)] = f2bf(v);
                }
            }
        }
    }
}

// ---------------- layer-1 aggregation: h1 = relu(s1 + mean_neigh(p1)), bf16 out -----
// one wave per node; lane covers ch {2l, 2l+1}; p1 is bf16 packed uint [M][64]
__global__ __launch_bounds__(256) void k_agg1_relu(const unsigned int* __restrict__ p,
                                                   const float* __restrict__ s1,
                                                   unsigned int* __restrict__ h1b,
                                                   const int* __restrict__ row_start,
                                                   const int* __restrict__ deg,
                                                   const int* __restrict__ csr_src, int n) {
    int gw = (blockIdx.x * 256 + threadIdx.x) >> 6;
    int lane = threadIdx.x & 63;
    if (gw >= n) return;
    int start = row_start[gw];
    int cnt = deg[gw];
    float sx = 0.f, sy = 0.f;
    int i = 0;
    for (; i + 4 <= cnt; i += 4) {
        int e0 = csr_src[start + i];
        int e1 = csr_src[start + i + 1];
        int e2 = csr_src[start + i + 2];
        int e3 = csr_src[start + i + 3];
        unsigned int v0 = p[e0 * 64 + lane];
        unsigned int v1 = p[e1 * 64 + lane];
        unsigned int v2 = p[e2 * 64 + lane];
        unsigned int v3 = p[e3 * 64 + lane];
        sx += bflo(v0) + bflo(v1) + bflo(v2) + bflo(v3);
        sy += bfhi(v0) + bfhi(v1) + bfhi(v2) + bfhi(v3);
    }
    for (; i < cnt; ++i) {
        unsigned int v = p[csr_src[start + i] * 64 + lane];
        sx += bflo(v);
        sy += bfhi(v);
    }
    float inv = 1.0f / fmaxf((float)cnt, 1.0f);
    float2 s = *(const float2*)&s1[gw * 128 + lane * 2];
    float rx = fmaxf(s.x + inv * sx, 0.f);
    float ry = fmaxf(s.y + inv * sy, 0.f);
    h1b[gw * 64 + lane] = pkbf(rx, ry);
}

// ---------------- layer-2 aggregation: out += mean_neigh(p2) (64 ch, bf16) ---------
__global__ __launch_bounds__(256) void k_agg2_add(const unsigned short* __restrict__ p,
                                                  float* __restrict__ out,
                                                  const int* __restrict__ row_start,
                                                  const int* __restrict__ deg,
                                                  const int* __restrict__ csr_src, int n) {
    int gw = (blockIdx.x * 256 + threadIdx.x) >> 6;
    int lane = threadIdx.x & 63;
    if (gw >= n) return;
    int start = row_start[gw];
    int cnt = deg[gw];
    float s = 0.f;
    int i = 0;
    for (; i + 4 <= cnt; i += 4) {
        int e0 = csr_src[start + i];
        int e1 = csr_src[start + i + 1];
        int e2 = csr_src[start + i + 2];
        int e3 = csr_src[start + i + 3];
        float a = (float)__uint_as_float((unsigned int)p[e0 * 64 + lane] << 16);
        float b = (float)__uint_as_float((unsigned int)p[e1 * 64 + lane] << 16);
        float c = (float)__uint_as_float((unsigned int)p[e2 * 64 + lane] << 16);
        float d = (float)__uint_as_float((unsigned int)p[e3 * 64 + lane] << 16);
        s += a + b + c + d;
    }
    for (; i < cnt; ++i)
        s += __uint_as_float((unsigned int)p[csr_src[start + i] * 64 + lane] << 16);
    float inv = 1.0f / fmaxf((float)cnt, 1.0f);
    out[gw * 64 + lane] += inv * s;
}

extern "C" void kernel_launch(void* const* d_in, const int* in_sizes, int n_in,
                              void* d_out, int out_size, void* d_ws, size_t ws_size,
                              hipStream_t stream) {
    const float* x   = (const float*)d_in[0];
    const int*   src = (const int*)d_in[1];
    const int*   dst = (const int*)d_in[2];
    const float* Ws1 = (const float*)d_in[3];
    const float* Wn1 = (const float*)d_in[4];
    const float* b1  = (const float*)d_in[5];
    const float* Ws2 = (const float*)d_in[6];
    const float* Wn2 = (const float*)d_in[7];
    const float* b2  = (const float*)d_in[8];
    float* out = (float*)d_out;
    const int N = in_sizes[0] / N_CH;  // 50000
    const int E = in_sizes[1];         // 800000

    // workspace layout (256B-aligned offsets)
    char* ws = (char*)d_ws;
    int* deg       = (int*)(ws + 0);          // N ints
    int* row_start = (int*)(ws + 200704);     // N ints
    int* cursor    = (int*)(ws + 401408);     // N ints
    int* bsum      = (int*)(ws + 602112);     // <=256 ints
    int* csr_src   = (int*)(ws + 603136);     // E ints (3.2 MB) -> 3803136
    unsigned short* p1 = (unsigned short*)(ws + 3803136);   // bf16 [N][128] 12.8MB -> 16603136
    float* s1          = (float*)(ws + 16603136);           // fp32 [N][128] 25.6MB -> 42203136
    unsigned short* p2 = (unsigned short*)(ws + 16603136);  // aliases s1 (used after agg1)
    unsigned short* h1b = (unsigned short*)(ws + 42203136); // bf16 [N][128] 12.8MB -> 55003136
    unsigned short* Bt1 = (unsigned short*)(ws + 55003136); // [256][128] bf16 64KB
    unsigned short* Bt2 = (unsigned short*)(ws + 55068672); // [128][128] bf16 32KB

    hipMemsetAsync(deg, 0, N * sizeof(int), stream);
    hipMemsetAsync(cursor, 0, N * sizeof(int), stream);

    const int eb = (E + 255) / 256;
    const int nb = (N + 255) / 256;  // 196 <= 256: single-block scan ok
    k_deg<<<eb, 256, 0, stream>>>(dst, deg, E);
    k_block_reduce<<<nb, 256, 0, stream>>>(deg, bsum, N);
    k_scan_bsum<<<1, 256, 0, stream>>>(bsum, nb);
    k_scan_final<<<nb, 256, 0, stream>>>(deg, bsum, row_start, N);
    k_fill_csr<<<eb, 256, 0, stream>>>(src, dst, row_start, cursor, csr_src, E);
    k_prep<<<192, 256, 0, stream>>>(Ws1, Wn1, Ws2, Wn2, Bt1, Bt2);

    const int gb = (N + 63) / 64;  // 782
    // layer 1: [s1 | p1] = x @ [Ws1 | Wn1] (+b1 on s1)
    k_gemm_dual<128, true><<<gb, 256, 0, stream>>>(x, Bt1, b1, s1, p1, N);
    k_agg1_relu<<<(N + 3) / 4, 256, 0, stream>>>((const unsigned int*)p1, s1, (unsigned int*)h1b,
                                                 row_start, deg, csr_src, N);
    // layer 2: [out | p2] = h1 @ [Ws2 | Wn2] (+b2 on out)
    k_gemm_dual<64, false><<<gb, 256, 0, stream>>>(h1b, Bt2, b2, out, p2, N);
    k_agg2_add<<<(N + 3) / 4, 256, 0, stream>>>(p2, out, row_start, deg, csr_src, N);
}

// Round 3
// 175.859 us; speedup vs baseline: 2.0679x; 1.2722x over previous
//
#include <hip/hip_runtime.h>

#define N_CH 128

typedef short bf16x8 __attribute__((ext_vector_type(8)));
typedef float f32x4 __attribute__((ext_vector_type(4)));

__device__ __forceinline__ unsigned short f2bf(float f) {
    unsigned int u = __float_as_uint(f);
    unsigned int r = (u + 0x7fffu + ((u >> 16) & 1u)) >> 16;
    return (unsigned short)r;
}
__device__ __forceinline__ unsigned int pkbf(float a, float b) {
    return (unsigned int)f2bf(a) | ((unsigned int)f2bf(b) << 16);
}
__device__ __forceinline__ float bflo(unsigned int v) { return __uint_as_float(v << 16); }
__device__ __forceinline__ float bfhi(unsigned int v) { return __uint_as_float(v & 0xffff0000u); }

// ---------------- degree histogram + per-edge rank (atomic return value) ----------
__global__ __launch_bounds__(256) void k_deg_rank(const int* __restrict__ dst,
                                                  int* __restrict__ deg,
                                                  int* __restrict__ rank, int e) {
    int i = blockIdx.x * 256 + threadIdx.x;
    if (i < e) {
        int r = atomicAdd(&deg[dst[i]], 1);
        rank[i] = r;
    }
}

// ---------------- 3-kernel exclusive scan over deg -> row_start ----------------
__global__ __launch_bounds__(256) void k_block_reduce(const int* __restrict__ deg,
                                                      int* __restrict__ bsum, int n) {
    __shared__ int sm[256];
    int i = blockIdx.x * 256 + threadIdx.x;
    sm[threadIdx.x] = (i < n) ? deg[i] : 0;
    __syncthreads();
    for (int s = 128; s > 0; s >>= 1) {
        if (threadIdx.x < s) sm[threadIdx.x] += sm[threadIdx.x + s];
        __syncthreads();
    }
    if (threadIdx.x == 0) bsum[blockIdx.x] = sm[0];
}

__global__ __launch_bounds__(256) void k_scan_bsum(int* bsum, int nb) {
    __shared__ int sm[256];
    int t = threadIdx.x;
    int v = (t < nb) ? bsum[t] : 0;
    sm[t] = v;
    __syncthreads();
    for (int off = 1; off < 256; off <<= 1) {
        int add = (t >= off) ? sm[t - off] : 0;
        __syncthreads();
        sm[t] += add;
        __syncthreads();
    }
    if (t < nb) bsum[t] = sm[t] - v;  // exclusive
}

__global__ __launch_bounds__(256) void k_scan_final(const int* __restrict__ deg,
                                                    const int* __restrict__ bsum,
                                                    int* __restrict__ row_start, int n) {
    __shared__ int sm[256];
    int t = threadIdx.x;
    int i = blockIdx.x * 256 + t;
    int v = (i < n) ? deg[i] : 0;
    sm[t] = v;
    __syncthreads();
    for (int off = 1; off < 256; off <<= 1) {
        int add = (t >= off) ? sm[t - off] : 0;
        __syncthreads();
        sm[t] += add;
        __syncthreads();
    }
    if (i < n) row_start[i] = bsum[blockIdx.x] + sm[t] - v;
}

// ---------------- CSR fill — NO atomics (rank precomputed) ----------------
__global__ __launch_bounds__(256) void k_fill_csr(const int* __restrict__ src,
                                                  const int* __restrict__ dst,
                                                  const int* __restrict__ rank,
                                                  const int* __restrict__ row_start,
                                                  int* __restrict__ csr_src, int e) {
    int i = blockIdx.x * 256 + threadIdx.x;
    if (i < e) {
        int d = dst[i];
        csr_src[row_start[d] + rank[i]] = src[i];
    }
}

// ---------------- weight prep: fp32 [K][N] -> bf16 transposed [n][k] ----------------
__global__ __launch_bounds__(256) void k_prep(const float* __restrict__ Ws1,
                                              const float* __restrict__ Wn1,
                                              const float* __restrict__ Ws2,
                                              const float* __restrict__ Wn2,
                                              unsigned short* __restrict__ Bt1,
                                              unsigned short* __restrict__ Bt2) {
    int idx = blockIdx.x * 256 + threadIdx.x;
    if (idx < 256 * 128) {
        int n = idx >> 7, k = idx & 127;
        const float* W = (n < 128) ? Ws1 : Wn1;
        Bt1[idx] = f2bf(W[k * 128 + (n & 127)]);
    } else {
        int j = idx - 256 * 128;
        if (j < 128 * 128) {
            int n = j >> 7, k = j & 127;
            const float* W = (n < 64) ? Ws2 : Wn2;
            Bt2[j] = f2bf(W[k * 64 + (n & 63)]);
        }
    }
}

// ---------------- dual MFMA GEMM: [S | P] = A[M x 128] @ [B0 | B1] ----------------
template <int NH, bool AF32>
__global__ __launch_bounds__(256) void k_gemm_dual(const void* __restrict__ Aptr,
                                                   const unsigned short* __restrict__ Bt,
                                                   const float* __restrict__ bias,
                                                   float* __restrict__ S,
                                                   unsigned short* __restrict__ P, int M) {
    constexpr int TN = 2 * NH;
    constexpr int WC = TN / 4;
    constexpr int NCT = WC / 16;
    __shared__ unsigned short As[64][128];
    __shared__ unsigned short Bs[TN][128];

    const int m0 = blockIdx.x * 64;
    const int tid = threadIdx.x;
    const int w = tid >> 6;
    const int l = tid & 63;

    if (AF32) {
        const float* A = (const float*)Aptr;
        for (int q = tid; q < 1024; q += 256) {
            int row = q >> 4, c = q & 15;
            int gr = m0 + row;
            uint4 o = make_uint4(0, 0, 0, 0);
            if (gr < M) {
                float4 f0 = *(const float4*)&A[gr * 128 + c * 8];
                float4 f1 = *(const float4*)&A[gr * 128 + c * 8 + 4];
                o.x = pkbf(f0.x, f0.y); o.y = pkbf(f0.z, f0.w);
                o.z = pkbf(f1.x, f1.y); o.w = pkbf(f1.z, f1.w);
            }
            *(uint4*)&As[row][(c ^ (row & 7)) * 8] = o;
        }
    } else {
        const uint4* A = (const uint4*)Aptr;
        for (int q = tid; q < 1024; q += 256) {
            int row = q >> 4, c = q & 15;
            int gr = m0 + row;
            uint4 v = make_uint4(0, 0, 0, 0);
            if (gr < M) v = A[gr * 16 + c];
            *(uint4*)&As[row][(c ^ (row & 7)) * 8] = v;
        }
    }
    {
        const uint4* B4 = (const uint4*)Bt;
        for (int q = tid; q < TN * 16; q += 256) {
            int n = q >> 4, c = q & 15;
            *(uint4*)&Bs[n][(c ^ (n & 7)) * 8] = B4[n * 16 + c];
        }
    }
    __syncthreads();

    const int fr = l & 15;
    const int kq = l >> 4;
    bf16x8 af[4][4];
#pragma unroll
    for (int rt = 0; rt < 4; ++rt) {
        int row = rt * 16 + fr;
#pragma unroll
        for (int kt = 0; kt < 4; ++kt) {
            int c = (kt * 4 + kq) ^ (row & 7);
            af[rt][kt] = *(bf16x8*)&As[row][c * 8];
        }
    }

    f32x4 acc[NCT][4] = {};
#pragma unroll
    for (int ct = 0; ct < NCT; ++ct) {
        int n = w * WC + ct * 16 + fr;
        bf16x8 bfr[4];
#pragma unroll
        for (int kt = 0; kt < 4; ++kt) {
            int c = (kt * 4 + kq) ^ (n & 7);
            bfr[kt] = *(bf16x8*)&Bs[n][c * 8];
        }
#pragma unroll
        for (int rt = 0; rt < 4; ++rt)
#pragma unroll
            for (int kt = 0; kt < 4; ++kt)
                acc[ct][rt] = __builtin_amdgcn_mfma_f32_16x16x32_bf16(af[rt][kt], bfr[kt],
                                                                      acc[ct][rt], 0, 0, 0);
    }

#pragma unroll
    for (int ct = 0; ct < NCT; ++ct) {
        int ncol = w * WC + ct * 16 + fr;
        bool isS = ncol < NH;
        float bv = isS ? bias[ncol] : 0.f;
#pragma unroll
        for (int rt = 0; rt < 4; ++rt) {
#pragma unroll
            for (int j = 0; j < 4; ++j) {
                int row = m0 + rt * 16 + (l >> 4) * 4 + j;
                if (row < M) {
                    float v = acc[ct][rt][j];
                    if (isS) S[row * NH + ncol] = v + bv;
                    else P[row * NH + (ncol - NH)] = f2bf(v);
                }
            }
        }
    }
}

// ---------------- layer-1 aggregation: h1 = relu(s1 + mean_neigh(p1)) ----------------
// one wave per node; 4 quarters of 16 lanes each gather a different neighbor row.
// p1: bf16 packed uint [N][64] (256B rows). lane (q, cl): uint4 at p[idx*64 + cl*4].
__global__ __launch_bounds__(256) void k_agg1_relu(const unsigned int* __restrict__ p,
                                                   const float* __restrict__ s1,
                                                   unsigned int* __restrict__ h1b,
                                                   const int* __restrict__ row_start,
                                                   const int* __restrict__ deg,
                                                   const int* __restrict__ csr, int n) {
    int gw = (blockIdx.x * 256 + threadIdx.x) >> 6;
    int lane = threadIdx.x & 63;
    if (gw >= n) return;
    int start = row_start[gw];
    int cnt = deg[gw];
    const int q = lane >> 4;
    const int cl = lane & 15;
    float a0 = 0.f, a1 = 0.f, a2 = 0.f, a3 = 0.f, a4 = 0.f, a5 = 0.f, a6 = 0.f, a7 = 0.f;
    int i = 0;
    for (; i + 8 <= cnt; i += 8) {
        int ia = csr[start + i + q];
        int ib = csr[start + i + 4 + q];
        uint4 va = *(const uint4*)&p[ia * 64 + cl * 4];
        uint4 vb = *(const uint4*)&p[ib * 64 + cl * 4];
        a0 += bflo(va.x) + bflo(vb.x); a1 += bfhi(va.x) + bfhi(vb.x);
        a2 += bflo(va.y) + bflo(vb.y); a3 += bfhi(va.y) + bfhi(vb.y);
        a4 += bflo(va.z) + bflo(vb.z); a5 += bfhi(va.z) + bfhi(vb.z);
        a6 += bflo(va.w) + bflo(vb.w); a7 += bfhi(va.w) + bfhi(vb.w);
    }
    for (; i < cnt; i += 4) {
        int nbi = i + q;
        if (nbi < cnt) {
            int ia = csr[start + nbi];
            uint4 va = *(const uint4*)&p[ia * 64 + cl * 4];
            a0 += bflo(va.x); a1 += bfhi(va.x);
            a2 += bflo(va.y); a3 += bfhi(va.y);
            a4 += bflo(va.z); a5 += bfhi(va.z);
            a6 += bflo(va.w); a7 += bfhi(va.w);
        }
    }
    // combine the 4 quarters
    a0 += __shfl_xor(a0, 16); a0 += __shfl_xor(a0, 32);
    a1 += __shfl_xor(a1, 16); a1 += __shfl_xor(a1, 32);
    a2 += __shfl_xor(a2, 16); a2 += __shfl_xor(a2, 32);
    a3 += __shfl_xor(a3, 16); a3 += __shfl_xor(a3, 32);
    a4 += __shfl_xor(a4, 16); a4 += __shfl_xor(a4, 32);
    a5 += __shfl_xor(a5, 16); a5 += __shfl_xor(a5, 32);
    a6 += __shfl_xor(a6, 16); a6 += __shfl_xor(a6, 32);
    a7 += __shfl_xor(a7, 16); a7 += __shfl_xor(a7, 32);

    float inv = 1.0f / fmaxf((float)cnt, 1.0f);
    if (q == 0) {
        float4 sa = *(const float4*)&s1[gw * 128 + cl * 8];
        float4 sb = *(const float4*)&s1[gw * 128 + cl * 8 + 4];
        float r0 = fmaxf(sa.x + inv * a0, 0.f);
        float r1 = fmaxf(sa.y + inv * a1, 0.f);
        float r2 = fmaxf(sa.z + inv * a2, 0.f);
        float r3 = fmaxf(sa.w + inv * a3, 0.f);
        float r4 = fmaxf(sb.x + inv * a4, 0.f);
        float r5 = fmaxf(sb.y + inv * a5, 0.f);
        float r6 = fmaxf(sb.z + inv * a6, 0.f);
        float r7 = fmaxf(sb.w + inv * a7, 0.f);
        uint4 o;
        o.x = pkbf(r0, r1); o.y = pkbf(r2, r3);
        o.z = pkbf(r4, r5); o.w = pkbf(r6, r7);
        *(uint4*)&h1b[gw * 64 + cl * 4] = o;
    }
}

// ---------------- layer-2 aggregation: out += mean_neigh(p2) (64 ch bf16) ----------
// p2: bf16 packed uint [N][32] (128B rows). lane (q, cl): uint2 at p[idx*32 + cl*2].
__global__ __launch_bounds__(256) void k_agg2_add(const unsigned int* __restrict__ p,
                                                  float* __restrict__ out,
                                                  const int* __restrict__ row_start,
                                                  const int* __restrict__ deg,
                                                  const int* __restrict__ csr, int n) {
    int gw = (blockIdx.x * 256 + threadIdx.x) >> 6;
    int lane = threadIdx.x & 63;
    if (gw >= n) return;
    int start = row_start[gw];
    int cnt = deg[gw];
    const int q = lane >> 4;
    const int cl = lane & 15;
    float a0 = 0.f, a1 = 0.f, a2 = 0.f, a3 = 0.f;
    int i = 0;
    for (; i + 8 <= cnt; i += 8) {
        int ia = csr[start + i + q];
        int ib = csr[start + i + 4 + q];
        uint2 va = *(const uint2*)&p[ia * 32 + cl * 2];
        uint2 vb = *(const uint2*)&p[ib * 32 + cl * 2];
        a0 += bflo(va.x) + bflo(vb.x); a1 += bfhi(va.x) + bfhi(vb.x);
        a2 += bflo(va.y) + bflo(vb.y); a3 += bfhi(va.y) + bfhi(vb.y);
    }
    for (; i < cnt; i += 4) {
        int nbi = i + q;
        if (nbi < cnt) {
            int ia = csr[start + nbi];
            uint2 va = *(const uint2*)&p[ia * 32 + cl * 2];
            a0 += bflo(va.x); a1 += bfhi(va.x);
            a2 += bflo(va.y); a3 += bfhi(va.y);
        }
    }
    a0 += __shfl_xor(a0, 16); a0 += __shfl_xor(a0, 32);
    a1 += __shfl_xor(a1, 16); a1 += __shfl_xor(a1, 32);
    a2 += __shfl_xor(a2, 16); a2 += __shfl_xor(a2, 32);
    a3 += __shfl_xor(a3, 16); a3 += __shfl_xor(a3, 32);
    float inv = 1.0f / fmaxf((float)cnt, 1.0f);
    if (q == 0) {
        float4 o = *(const float4*)&out[gw * 64 + cl * 4];
        o.x += inv * a0; o.y += inv * a1; o.z += inv * a2; o.w += inv * a3;
        *(float4*)&out[gw * 64 + cl * 4] = o;
    }
}

extern "C" void kernel_launch(void* const* d_in, const int* in_sizes, int n_in,
                              void* d_out, int out_size, void* d_ws, size_t ws_size,
                              hipStream_t stream) {
    const float* x   = (const float*)d_in[0];
    const int*   src = (const int*)d_in[1];
    const int*   dst = (const int*)d_in[2];
    const float* Ws1 = (const float*)d_in[3];
    const float* Wn1 = (const float*)d_in[4];
    const float* b1  = (const float*)d_in[5];
    const float* Ws2 = (const float*)d_in[6];
    const float* Wn2 = (const float*)d_in[7];
    const float* b2  = (const float*)d_in[8];
    float* out = (float*)d_out;
    const int N = in_sizes[0] / N_CH;  // 50000
    const int E = in_sizes[1];         // 800000

    // workspace layout (256B-aligned). rank is dead after k_fill_csr; p1 aliases it.
    char* ws = (char*)d_ws;
    int* deg       = (int*)(ws + 0);          // N ints -> 200704
    int* row_start = (int*)(ws + 200704);     // N ints -> 401408
    int* bsum      = (int*)(ws + 401408);     // <=256 ints -> 402432
    int* csr_src   = (int*)(ws + 402432);     // E ints -> 3602432 (persists)
    int* rank      = (int*)(ws + 3602432);    // E ints -> 6802432 (dead after fill)
    unsigned short* p1 = (unsigned short*)(ws + 3602432);   // bf16 [N][128] -> 16402432 (aliases rank, written after)
    float* s1          = (float*)(ws + 16402432);           // fp32 [N][128] -> 42002432
    unsigned short* p2 = (unsigned short*)(ws + 16402432);  // aliases s1 (after agg1)
    unsigned short* h1b = (unsigned short*)(ws + 42002432); // bf16 [N][128] -> 54802432
    unsigned short* Bt1 = (unsigned short*)(ws + 54802432); // 64KB -> 54867968
    unsigned short* Bt2 = (unsigned short*)(ws + 54867968); // 32KB -> 54900736

    hipMemsetAsync(deg, 0, N * sizeof(int), stream);

    const int eb = (E + 255) / 256;
    const int nb = (N + 255) / 256;  // 196 <= 256: single-block scan ok
    k_deg_rank<<<eb, 256, 0, stream>>>(dst, deg, rank, E);
    k_block_reduce<<<nb, 256, 0, stream>>>(deg, bsum, N);
    k_scan_bsum<<<1, 256, 0, stream>>>(bsum, nb);
    k_scan_final<<<nb, 256, 0, stream>>>(deg, bsum, row_start, N);
    k_fill_csr<<<eb, 256, 0, stream>>>(src, dst, rank, row_start, csr_src, E);
    k_prep<<<192, 256, 0, stream>>>(Ws1, Wn1, Ws2, Wn2, Bt1, Bt2);

    const int gb = (N + 63) / 64;  // 782
    // layer 1: [s1 | p1] = x @ [Ws1 | Wn1] (+b1 on s1)
    k_gemm_dual<128, true><<<gb, 256, 0, stream>>>(x, Bt1, b1, s1, p1, N);
    k_agg1_relu<<<(N + 3) / 4, 256, 0, stream>>>((const unsigned int*)p1, s1, (unsigned int*)h1b,
                                                 row_start, deg, csr_src, N);
    // layer 2: [out | p2] = h1 @ [Ws2 | Wn2] (+b2 on out)
    k_gemm_dual<64, false><<<gb, 256, 0, stream>>>(h1b, Bt2, b2, out, (unsigned short*)p2, N);
    k_agg2_add<<<(N + 3) / 4, 256, 0, stream>>>((const unsigned int*)p2, out, row_start, deg, csr_src, N);
}

// Round 4
// 172.426 us; speedup vs baseline: 2.1091x; 1.0199x over previous
//
#include <hip/hip_runtime.h>

#define N_CH 128

typedef short bf16x8 __attribute__((ext_vector_type(8)));
typedef float f32x4 __attribute__((ext_vector_type(4)));

__device__ __forceinline__ unsigned short f2bf(float f) {
    unsigned int u = __float_as_uint(f);
    unsigned int r = (u + 0x7fffu + ((u >> 16) & 1u)) >> 16;
    return (unsigned short)r;
}
__device__ __forceinline__ unsigned int pkbf(float a, float b) {
    return (unsigned int)f2bf(a) | ((unsigned int)f2bf(b) << 16);
}
__device__ __forceinline__ float bflo(unsigned int v) { return __uint_as_float(v << 16); }
__device__ __forceinline__ float bfhi(unsigned int v) { return __uint_as_float(v & 0xffff0000u); }

// ---------------- zero-fill (replaces pathologically slow hipMemsetAsync) ---------
__global__ __launch_bounds__(256) void k_zero(uint4* __restrict__ p, int n4) {
    int i = blockIdx.x * 256 + threadIdx.x;
    if (i < n4) p[i] = make_uint4(0, 0, 0, 0);
}

// ---------------- degree histogram + per-edge rank (atomic return value) ----------
__global__ __launch_bounds__(256) void k_deg_rank(const int* __restrict__ dst,
                                                  int* __restrict__ deg,
                                                  int* __restrict__ rank, int e) {
    int i = blockIdx.x * 256 + threadIdx.x;
    if (i < e) {
        int r = atomicAdd(&deg[dst[i]], 1);
        rank[i] = r;
    }
}

// ---------------- 3-kernel exclusive scan over deg -> row_start ----------------
__global__ __launch_bounds__(256) void k_block_reduce(const int* __restrict__ deg,
                                                      int* __restrict__ bsum, int n) {
    __shared__ int sm[256];
    int i = blockIdx.x * 256 + threadIdx.x;
    sm[threadIdx.x] = (i < n) ? deg[i] : 0;
    __syncthreads();
    for (int s = 128; s > 0; s >>= 1) {
        if (threadIdx.x < s) sm[threadIdx.x] += sm[threadIdx.x + s];
        __syncthreads();
    }
    if (threadIdx.x == 0) bsum[blockIdx.x] = sm[0];
}

__global__ __launch_bounds__(256) void k_scan_bsum(int* bsum, int nb) {
    __shared__ int sm[256];
    int t = threadIdx.x;
    int v = (t < nb) ? bsum[t] : 0;
    sm[t] = v;
    __syncthreads();
    for (int off = 1; off < 256; off <<= 1) {
        int add = (t >= off) ? sm[t - off] : 0;
        __syncthreads();
        sm[t] += add;
        __syncthreads();
    }
    if (t < nb) bsum[t] = sm[t] - v;  // exclusive
}

__global__ __launch_bounds__(256) void k_scan_final(const int* __restrict__ deg,
                                                    const int* __restrict__ bsum,
                                                    int* __restrict__ row_start, int n) {
    __shared__ int sm[256];
    int t = threadIdx.x;
    int i = blockIdx.x * 256 + t;
    int v = (i < n) ? deg[i] : 0;
    sm[t] = v;
    __syncthreads();
    for (int off = 1; off < 256; off <<= 1) {
        int add = (t >= off) ? sm[t - off] : 0;
        __syncthreads();
        sm[t] += add;
        __syncthreads();
    }
    if (i < n) row_start[i] = bsum[blockIdx.x] + sm[t] - v;
}

// ---------------- CSR fill — NO atomics (rank precomputed) ----------------
__global__ __launch_bounds__(256) void k_fill_csr(const int* __restrict__ src,
                                                  const int* __restrict__ dst,
                                                  const int* __restrict__ rank,
                                                  const int* __restrict__ row_start,
                                                  int* __restrict__ csr_src, int e) {
    int i = blockIdx.x * 256 + threadIdx.x;
    if (i < e) {
        int d = dst[i];
        csr_src[row_start[d] + rank[i]] = src[i];
    }
}

// ---------------- weight prep: fp32 [K][N] -> bf16 transposed [n][k] ----------------
__global__ __launch_bounds__(256) void k_prep(const float* __restrict__ Ws1,
                                              const float* __restrict__ Wn1,
                                              const float* __restrict__ Ws2,
                                              const float* __restrict__ Wn2,
                                              unsigned short* __restrict__ Bt1,
                                              unsigned short* __restrict__ Bt2) {
    int idx = blockIdx.x * 256 + threadIdx.x;
    if (idx < 256 * 128) {
        int n = idx >> 7, k = idx & 127;
        const float* W = (n < 128) ? Ws1 : Wn1;
        Bt1[idx] = f2bf(W[k * 128 + (n & 127)]);
    } else {
        int j = idx - 256 * 128;
        if (j < 128 * 128) {
            int n = j >> 7, k = j & 127;
            const float* W = (n < 64) ? Ws2 : Wn2;
            Bt2[j] = f2bf(W[k * 64 + (n & 63)]);
        }
    }
}

// ---------------- dual MFMA GEMM: [S | P] = A[M x 128] @ [B0 | B1] ----------------
template <int NH, bool AF32>
__global__ __launch_bounds__(256) void k_gemm_dual(const void* __restrict__ Aptr,
                                                   const unsigned short* __restrict__ Bt,
                                                   const float* __restrict__ bias,
                                                   float* __restrict__ S,
                                                   unsigned short* __restrict__ P, int M) {
    constexpr int TN = 2 * NH;
    constexpr int WC = TN / 4;
    constexpr int NCT = WC / 16;
    __shared__ unsigned short As[64][128];
    __shared__ unsigned short Bs[TN][128];

    const int m0 = blockIdx.x * 64;
    const int tid = threadIdx.x;
    const int w = tid >> 6;
    const int l = tid & 63;

    if (AF32) {
        const float* A = (const float*)Aptr;
        for (int q = tid; q < 1024; q += 256) {
            int row = q >> 4, c = q & 15;
            int gr = m0 + row;
            uint4 o = make_uint4(0, 0, 0, 0);
            if (gr < M) {
                float4 f0 = *(const float4*)&A[gr * 128 + c * 8];
                float4 f1 = *(const float4*)&A[gr * 128 + c * 8 + 4];
                o.x = pkbf(f0.x, f0.y); o.y = pkbf(f0.z, f0.w);
                o.z = pkbf(f1.x, f1.y); o.w = pkbf(f1.z, f1.w);
            }
            *(uint4*)&As[row][(c ^ (row & 7)) * 8] = o;
        }
    } else {
        const uint4* A = (const uint4*)Aptr;
        for (int q = tid; q < 1024; q += 256) {
            int row = q >> 4, c = q & 15;
            int gr = m0 + row;
            uint4 v = make_uint4(0, 0, 0, 0);
            if (gr < M) v = A[gr * 16 + c];
            *(uint4*)&As[row][(c ^ (row & 7)) * 8] = v;
        }
    }
    {
        const uint4* B4 = (const uint4*)Bt;
        for (int q = tid; q < TN * 16; q += 256) {
            int n = q >> 4, c = q & 15;
            *(uint4*)&Bs[n][(c ^ (n & 7)) * 8] = B4[n * 16 + c];
        }
    }
    __syncthreads();

    const int fr = l & 15;
    const int kq = l >> 4;
    bf16x8 af[4][4];
#pragma unroll
    for (int rt = 0; rt < 4; ++rt) {
        int row = rt * 16 + fr;
#pragma unroll
        for (int kt = 0; kt < 4; ++kt) {
            int c = (kt * 4 + kq) ^ (row & 7);
            af[rt][kt] = *(bf16x8*)&As[row][c * 8];
        }
    }

    f32x4 acc[NCT][4] = {};
#pragma unroll
    for (int ct = 0; ct < NCT; ++ct) {
        int n = w * WC + ct * 16 + fr;
        bf16x8 bfr[4];
#pragma unroll
        for (int kt = 0; kt < 4; ++kt) {
            int c = (kt * 4 + kq) ^ (n & 7);
            bfr[kt] = *(bf16x8*)&Bs[n][c * 8];
        }
#pragma unroll
        for (int rt = 0; rt < 4; ++rt)
#pragma unroll
            for (int kt = 0; kt < 4; ++kt)
                acc[ct][rt] = __builtin_amdgcn_mfma_f32_16x16x32_bf16(af[rt][kt], bfr[kt],
                                                                      acc[ct][rt], 0, 0, 0);
    }

#pragma unroll
    for (int ct = 0; ct < NCT; ++ct) {
        int ncol = w * WC + ct * 16 + fr;
        bool isS = ncol < NH;
        float bv = isS ? bias[ncol] : 0.f;
#pragma unroll
        for (int rt = 0; rt < 4; ++rt) {
#pragma unroll
            for (int j = 0; j < 4; ++j) {
                int row = m0 + rt * 16 + (l >> 4) * 4 + j;
                if (row < M) {
                    float v = acc[ct][rt][j];
                    if (isS) S[row * NH + ncol] = v + bv;
                    else P[row * NH + (ncol - NH)] = f2bf(v);
                }
            }
        }
    }
}

// ---------------- layer-1 aggregation: h1 = relu(s1 + mean_neigh(p1)) ----------------
// one wave per node; 4 quarters of 16 lanes; 4-deep unroll (16 rows in flight).
// p1: bf16 packed uint [N][64] (256B rows). lane (q, cl): uint4 at p[idx*64 + cl*4].
__global__ __launch_bounds__(256) void k_agg1_relu(const unsigned int* __restrict__ p,
                                                   const float* __restrict__ s1,
                                                   unsigned int* __restrict__ h1b,
                                                   const int* __restrict__ row_start,
                                                   const int* __restrict__ deg,
                                                   const int* __restrict__ csr, int n) {
    int gw = (blockIdx.x * 256 + threadIdx.x) >> 6;
    int lane = threadIdx.x & 63;
    if (gw >= n) return;
    int start = row_start[gw];
    int cnt = deg[gw];
    const int q = lane >> 4;
    const int cl = lane & 15;
    float a0 = 0.f, a1 = 0.f, a2 = 0.f, a3 = 0.f, a4 = 0.f, a5 = 0.f, a6 = 0.f, a7 = 0.f;
    int i = 0;
    for (; i + 16 <= cnt; i += 16) {
        int e0 = csr[start + i + q];
        int e1 = csr[start + i + 4 + q];
        int e2 = csr[start + i + 8 + q];
        int e3 = csr[start + i + 12 + q];
        uint4 v0 = *(const uint4*)&p[e0 * 64 + cl * 4];
        uint4 v1 = *(const uint4*)&p[e1 * 64 + cl * 4];
        uint4 v2 = *(const uint4*)&p[e2 * 64 + cl * 4];
        uint4 v3 = *(const uint4*)&p[e3 * 64 + cl * 4];
        a0 += bflo(v0.x) + bflo(v1.x) + bflo(v2.x) + bflo(v3.x);
        a1 += bfhi(v0.x) + bfhi(v1.x) + bfhi(v2.x) + bfhi(v3.x);
        a2 += bflo(v0.y) + bflo(v1.y) + bflo(v2.y) + bflo(v3.y);
        a3 += bfhi(v0.y) + bfhi(v1.y) + bfhi(v2.y) + bfhi(v3.y);
        a4 += bflo(v0.z) + bflo(v1.z) + bflo(v2.z) + bflo(v3.z);
        a5 += bfhi(v0.z) + bfhi(v1.z) + bfhi(v2.z) + bfhi(v3.z);
        a6 += bflo(v0.w) + bflo(v1.w) + bflo(v2.w) + bflo(v3.w);
        a7 += bfhi(v0.w) + bfhi(v1.w) + bfhi(v2.w) + bfhi(v3.w);
    }
    if (i + 8 <= cnt) {
        int e0 = csr[start + i + q];
        int e1 = csr[start + i + 4 + q];
        uint4 v0 = *(const uint4*)&p[e0 * 64 + cl * 4];
        uint4 v1 = *(const uint4*)&p[e1 * 64 + cl * 4];
        a0 += bflo(v0.x) + bflo(v1.x); a1 += bfhi(v0.x) + bfhi(v1.x);
        a2 += bflo(v0.y) + bflo(v1.y); a3 += bfhi(v0.y) + bfhi(v1.y);
        a4 += bflo(v0.z) + bflo(v1.z); a5 += bfhi(v0.z) + bfhi(v1.z);
        a6 += bflo(v0.w) + bflo(v1.w); a7 += bfhi(v0.w) + bfhi(v1.w);
        i += 8;
    }
    for (; i < cnt; i += 4) {
        int nbi = i + q;
        if (nbi < cnt) {
            int ia = csr[start + nbi];
            uint4 va = *(const uint4*)&p[ia * 64 + cl * 4];
            a0 += bflo(va.x); a1 += bfhi(va.x);
            a2 += bflo(va.y); a3 += bfhi(va.y);
            a4 += bflo(va.z); a5 += bfhi(va.z);
            a6 += bflo(va.w); a7 += bfhi(va.w);
        }
    }
    // combine the 4 quarters
    a0 += __shfl_xor(a0, 16); a0 += __shfl_xor(a0, 32);
    a1 += __shfl_xor(a1, 16); a1 += __shfl_xor(a1, 32);
    a2 += __shfl_xor(a2, 16); a2 += __shfl_xor(a2, 32);
    a3 += __shfl_xor(a3, 16); a3 += __shfl_xor(a3, 32);
    a4 += __shfl_xor(a4, 16); a4 += __shfl_xor(a4, 32);
    a5 += __shfl_xor(a5, 16); a5 += __shfl_xor(a5, 32);
    a6 += __shfl_xor(a6, 16); a6 += __shfl_xor(a6, 32);
    a7 += __shfl_xor(a7, 16); a7 += __shfl_xor(a7, 32);

    float inv = 1.0f / fmaxf((float)cnt, 1.0f);
    if (q == 0) {
        float4 sa = *(const float4*)&s1[gw * 128 + cl * 8];
        float4 sb = *(const float4*)&s1[gw * 128 + cl * 8 + 4];
        float r0 = fmaxf(sa.x + inv * a0, 0.f);
        float r1 = fmaxf(sa.y + inv * a1, 0.f);
        float r2 = fmaxf(sa.z + inv * a2, 0.f);
        float r3 = fmaxf(sa.w + inv * a3, 0.f);
        float r4 = fmaxf(sb.x + inv * a4, 0.f);
        float r5 = fmaxf(sb.y + inv * a5, 0.f);
        float r6 = fmaxf(sb.z + inv * a6, 0.f);
        float r7 = fmaxf(sb.w + inv * a7, 0.f);
        uint4 o;
        o.x = pkbf(r0, r1); o.y = pkbf(r2, r3);
        o.z = pkbf(r4, r5); o.w = pkbf(r6, r7);
        *(uint4*)&h1b[gw * 64 + cl * 4] = o;
    }
}

// ---------------- layer-2 aggregation: out += mean_neigh(p2) (64 ch bf16) ----------
// 8 groups of 8 lanes; each group gathers one 128B row via uint4 (8 rows/instr).
// p2: bf16 packed uint [N][32]. lane (g, cl): uint4 at p[idx*32 + cl*4].
__global__ __launch_bounds__(256) void k_agg2_add(const unsigned int* __restrict__ p,
                                                  float* __restrict__ out,
                                                  const int* __restrict__ row_start,
                                                  const int* __restrict__ deg,
                                                  const int* __restrict__ csr, int n) {
    int gw = (blockIdx.x * 256 + threadIdx.x) >> 6;
    int lane = threadIdx.x & 63;
    if (gw >= n) return;
    int start = row_start[gw];
    int cnt = deg[gw];
    const int g = lane >> 3;   // 8 groups
    const int cl = lane & 7;   // 8 lanes per group; covers ch [cl*8, cl*8+8)
    float a0 = 0.f, a1 = 0.f, a2 = 0.f, a3 = 0.f, a4 = 0.f, a5 = 0.f, a6 = 0.f, a7 = 0.f;
    int i = 0;
    for (; i + 16 <= cnt; i += 16) {
        int e0 = csr[start + i + g];
        int e1 = csr[start + i + 8 + g];
        uint4 v0 = *(const uint4*)&p[e0 * 32 + cl * 4];
        uint4 v1 = *(const uint4*)&p[e1 * 32 + cl * 4];
        a0 += bflo(v0.x) + bflo(v1.x); a1 += bfhi(v0.x) + bfhi(v1.x);
        a2 += bflo(v0.y) + bflo(v1.y); a3 += bfhi(v0.y) + bfhi(v1.y);
        a4 += bflo(v0.z) + bflo(v1.z); a5 += bfhi(v0.z) + bfhi(v1.z);
        a6 += bflo(v0.w) + bflo(v1.w); a7 += bfhi(v0.w) + bfhi(v1.w);
    }
    for (; i < cnt; i += 8) {
        int nbi = i + g;
        if (nbi < cnt) {
            int ia = csr[start + nbi];
            uint4 va = *(const uint4*)&p[ia * 32 + cl * 4];
            a0 += bflo(va.x); a1 += bfhi(va.x);
            a2 += bflo(va.y); a3 += bfhi(va.y);
            a4 += bflo(va.z); a5 += bfhi(va.z);
            a6 += bflo(va.w); a7 += bfhi(va.w);
        }
    }
    // combine the 8 groups
    a0 += __shfl_xor(a0, 8); a0 += __shfl_xor(a0, 16); a0 += __shfl_xor(a0, 32);
    a1 += __shfl_xor(a1, 8); a1 += __shfl_xor(a1, 16); a1 += __shfl_xor(a1, 32);
    a2 += __shfl_xor(a2, 8); a2 += __shfl_xor(a2, 16); a2 += __shfl_xor(a2, 32);
    a3 += __shfl_xor(a3, 8); a3 += __shfl_xor(a3, 16); a3 += __shfl_xor(a3, 32);
    a4 += __shfl_xor(a4, 8); a4 += __shfl_xor(a4, 16); a4 += __shfl_xor(a4, 32);
    a5 += __shfl_xor(a5, 8); a5 += __shfl_xor(a5, 16); a5 += __shfl_xor(a5, 32);
    a6 += __shfl_xor(a6, 8); a6 += __shfl_xor(a6, 16); a6 += __shfl_xor(a6, 32);
    a7 += __shfl_xor(a7, 8); a7 += __shfl_xor(a7, 16); a7 += __shfl_xor(a7, 32);
    float inv = 1.0f / fmaxf((float)cnt, 1.0f);
    if (g == 0) {
        float4 oa = *(const float4*)&out[gw * 64 + cl * 8];
        float4 ob = *(const float4*)&out[gw * 64 + cl * 8 + 4];
        oa.x += inv * a0; oa.y += inv * a1; oa.z += inv * a2; oa.w += inv * a3;
        ob.x += inv * a4; ob.y += inv * a5; ob.z += inv * a6; ob.w += inv * a7;
        *(float4*)&out[gw * 64 + cl * 8] = oa;
        *(float4*)&out[gw * 64 + cl * 8 + 4] = ob;
    }
}

extern "C" void kernel_launch(void* const* d_in, const int* in_sizes, int n_in,
                              void* d_out, int out_size, void* d_ws, size_t ws_size,
                              hipStream_t stream) {
    const float* x   = (const float*)d_in[0];
    const int*   src = (const int*)d_in[1];
    const int*   dst = (const int*)d_in[2];
    const float* Ws1 = (const float*)d_in[3];
    const float* Wn1 = (const float*)d_in[4];
    const float* b1  = (const float*)d_in[5];
    const float* Ws2 = (const float*)d_in[6];
    const float* Wn2 = (const float*)d_in[7];
    const float* b2  = (const float*)d_in[8];
    float* out = (float*)d_out;
    const int N = in_sizes[0] / N_CH;  // 50000
    const int E = in_sizes[1];         // 800000

    // workspace layout (256B-aligned). rank dead after fill; p1 aliases it.
    char* ws = (char*)d_ws;
    int* deg       = (int*)(ws + 0);          // N ints -> 200704
    int* row_start = (int*)(ws + 200704);     // N ints -> 401408
    int* bsum      = (int*)(ws + 401408);     // <=256 ints -> 402432
    int* csr_src   = (int*)(ws + 402432);     // E ints -> 3602432 (persists)
    int* rank      = (int*)(ws + 3602432);    // E ints -> 6802432 (dead after fill)
    unsigned short* p1 = (unsigned short*)(ws + 3602432);   // bf16 [N][128] (aliases rank)
    float* s1          = (float*)(ws + 16402432);           // fp32 [N][128]
    unsigned short* p2 = (unsigned short*)(ws + 16402432);  // aliases s1 (after agg1)
    unsigned short* h1b = (unsigned short*)(ws + 42002432); // bf16 [N][128]
    unsigned short* Bt1 = (unsigned short*)(ws + 54802432); // 64KB
    unsigned short* Bt2 = (unsigned short*)(ws + 54867968); // 32KB

    const int eb = (E + 255) / 256;
    const int nb = (N + 255) / 256;  // 196 <= 256: single-block scan ok
    const int z4 = (N + 3) / 4;      // uint4 count for deg zero
    k_zero<<<(z4 + 255) / 256, 256, 0, stream>>>((uint4*)deg, z4);
    k_deg_rank<<<eb, 256, 0, stream>>>(dst, deg, rank, E);
    k_block_reduce<<<nb, 256, 0, stream>>>(deg, bsum, N);
    k_scan_bsum<<<1, 256, 0, stream>>>(bsum, nb);
    k_scan_final<<<nb, 256, 0, stream>>>(deg, bsum, row_start, N);
    k_fill_csr<<<eb, 256, 0, stream>>>(src, dst, rank, row_start, csr_src, E);
    k_prep<<<192, 256, 0, stream>>>(Ws1, Wn1, Ws2, Wn2, Bt1, Bt2);

    const int gb = (N + 63) / 64;  // 782
    // layer 1: [s1 | p1] = x @ [Ws1 | Wn1] (+b1 on s1)
    k_gemm_dual<128, true><<<gb, 256, 0, stream>>>(x, Bt1, b1, s1, p1, N);
    k_agg1_relu<<<(N + 3) / 4, 256, 0, stream>>>((const unsigned int*)p1, s1, (unsigned int*)h1b,
                                                 row_start, deg, csr_src, N);
    // layer 2: [out | p2] = h1 @ [Ws2 | Wn2] (+b2 on out)
    k_gemm_dual<64, false><<<gb, 256, 0, stream>>>(h1b, Bt2, b2, out, (unsigned short*)p2, N);
    k_agg2_add<<<(N + 3) / 4, 256, 0, stream>>>((const unsigned int*)p2, out, row_start, deg, csr_src, N);
}

// Round 5
// 149.022 us; speedup vs baseline: 2.4403x; 1.1570x over previous
//
#include <hip/hip_runtime.h>

#define N_CH 128

typedef short bf16x8 __attribute__((ext_vector_type(8)));
typedef float f32x4 __attribute__((ext_vector_type(4)));

__device__ __forceinline__ unsigned short f2bf(float f) {
    unsigned int u = __float_as_uint(f);
    unsigned int r = (u + 0x7fffu + ((u >> 16) & 1u)) >> 16;
    return (unsigned short)r;
}
__device__ __forceinline__ unsigned int pkbf(float a, float b) {
    return (unsigned int)f2bf(a) | ((unsigned int)f2bf(b) << 16);
}
__device__ __forceinline__ float bflo(unsigned int v) { return __uint_as_float(v << 16); }
__device__ __forceinline__ float bfhi(unsigned int v) { return __uint_as_float(v & 0xffff0000u); }

// ---------------- fused init: zero deg | prep Bt1/Bt2 | cast x -> bf16 -------------
// Bt1: [128 n][256 k]  (k<128 from Ws1, k>=128 from Wn1)   h1 = [x|xagg] @ Bt1^T
// Bt2: [128 n][128 k]  (n<64 from Ws2 -> S half, n>=64 from Wn2 -> P half)
__global__ __launch_bounds__(256) void k_init(const float* __restrict__ x,
                                              const float* __restrict__ Ws1,
                                              const float* __restrict__ Wn1,
                                              const float* __restrict__ Ws2,
                                              const float* __restrict__ Wn2,
                                              int* __restrict__ deg,
                                              unsigned short* __restrict__ Bt1,
                                              unsigned short* __restrict__ Bt2,
                                              uint4* __restrict__ xb4,
                                              int ndeg4, int nxq) {
    int b = blockIdx.x, t = threadIdx.x;
    if (b < 49) {
        int i = b * 256 + t;
        if (i < ndeg4) ((uint4*)deg)[i] = make_uint4(0, 0, 0, 0);
    } else if (b < 241) {
        int idx = (b - 49) * 256 + t;
        if (idx < 128 * 256) {  // Bt1
            int n = idx >> 8, k = idx & 255;
            float v = (k < 128) ? Ws1[k * 128 + n] : Wn1[(k - 128) * 128 + n];
            Bt1[idx] = f2bf(v);
        } else {  // Bt2 (16384 elems)
            int j = idx - 128 * 256;
            int n = j >> 7, k = j & 127;
            float v = (n < 64) ? Ws2[k * 64 + n] : Wn2[k * 64 + (n - 64)];
            Bt2[j] = f2bf(v);
        }
    } else {
        int q = (b - 241) * 256 + t;
        if (q < nxq) {
            const float4* xf = (const float4*)x;
            float4 f0 = xf[2 * q], f1 = xf[2 * q + 1];
            uint4 o;
            o.x = pkbf(f0.x, f0.y); o.y = pkbf(f0.z, f0.w);
            o.z = pkbf(f1.x, f1.y); o.w = pkbf(f1.z, f1.w);
            xb4[q] = o;
        }
    }
}

// ---------------- degree histogram + per-edge rank (atomic return value) ----------
__global__ __launch_bounds__(256) void k_deg_rank(const int* __restrict__ dst,
                                                  int* __restrict__ deg,
                                                  int* __restrict__ rank, int e) {
    int i = blockIdx.x * 256 + threadIdx.x;
    if (i < e) {
        int r = atomicAdd(&deg[dst[i]], 1);
        rank[i] = r;
    }
}

// ---------------- 3-kernel exclusive scan over deg -> row_start ----------------
__global__ __launch_bounds__(256) void k_block_reduce(const int* __restrict__ deg,
                                                      int* __restrict__ bsum, int n) {
    __shared__ int sm[256];
    int i = blockIdx.x * 256 + threadIdx.x;
    sm[threadIdx.x] = (i < n) ? deg[i] : 0;
    __syncthreads();
    for (int s = 128; s > 0; s >>= 1) {
        if (threadIdx.x < s) sm[threadIdx.x] += sm[threadIdx.x + s];
        __syncthreads();
    }
    if (threadIdx.x == 0) bsum[blockIdx.x] = sm[0];
}

__global__ __launch_bounds__(256) void k_scan_bsum(int* bsum, int nb) {
    __shared__ int sm[256];
    int t = threadIdx.x;
    int v = (t < nb) ? bsum[t] : 0;
    sm[t] = v;
    __syncthreads();
    for (int off = 1; off < 256; off <<= 1) {
        int add = (t >= off) ? sm[t - off] : 0;
        __syncthreads();
        sm[t] += add;
        __syncthreads();
    }
    if (t < nb) bsum[t] = sm[t] - v;  // exclusive
}

__global__ __launch_bounds__(256) void k_scan_final(const int* __restrict__ deg,
                                                    const int* __restrict__ bsum,
                                                    int* __restrict__ row_start, int n) {
    __shared__ int sm[256];
    int t = threadIdx.x;
    int i = blockIdx.x * 256 + t;
    int v = (i < n) ? deg[i] : 0;
    sm[t] = v;
    __syncthreads();
    for (int off = 1; off < 256; off <<= 1) {
        int add = (t >= off) ? sm[t - off] : 0;
        __syncthreads();
        sm[t] += add;
        __syncthreads();
    }
    if (i < n) row_start[i] = bsum[blockIdx.x] + sm[t] - v;
}

// ---------------- CSR fill — NO atomics (rank precomputed) ----------------
__global__ __launch_bounds__(256) void k_fill_csr(const int* __restrict__ src,
                                                  const int* __restrict__ dst,
                                                  const int* __restrict__ rank,
                                                  const int* __restrict__ row_start,
                                                  int* __restrict__ csr_src, int e) {
    int i = blockIdx.x * 256 + threadIdx.x;
    if (i < e) {
        int d = dst[i];
        csr_src[row_start[d] + rank[i]] = src[i];
    }
}

// ---------------- neighbor-mean of x (bf16): xagg = mean(xb[neigh]) ----------------
// one wave per node; 4 quarters of 16 lanes; 4-deep unroll (16 rows in flight).
__global__ __launch_bounds__(256) void k_aggx(const unsigned int* __restrict__ p,
                                              unsigned int* __restrict__ xagg,
                                              const int* __restrict__ row_start,
                                              const int* __restrict__ deg,
                                              const int* __restrict__ csr, int n) {
    int gw = (blockIdx.x * 256 + threadIdx.x) >> 6;
    int lane = threadIdx.x & 63;
    if (gw >= n) return;
    int start = row_start[gw];
    int cnt = deg[gw];
    const int q = lane >> 4;
    const int cl = lane & 15;
    float a0 = 0.f, a1 = 0.f, a2 = 0.f, a3 = 0.f, a4 = 0.f, a5 = 0.f, a6 = 0.f, a7 = 0.f;
    int i = 0;
    for (; i + 16 <= cnt; i += 16) {
        int e0 = csr[start + i + q];
        int e1 = csr[start + i + 4 + q];
        int e2 = csr[start + i + 8 + q];
        int e3 = csr[start + i + 12 + q];
        uint4 v0 = *(const uint4*)&p[e0 * 64 + cl * 4];
        uint4 v1 = *(const uint4*)&p[e1 * 64 + cl * 4];
        uint4 v2 = *(const uint4*)&p[e2 * 64 + cl * 4];
        uint4 v3 = *(const uint4*)&p[e3 * 64 + cl * 4];
        a0 += bflo(v0.x) + bflo(v1.x) + bflo(v2.x) + bflo(v3.x);
        a1 += bfhi(v0.x) + bfhi(v1.x) + bfhi(v2.x) + bfhi(v3.x);
        a2 += bflo(v0.y) + bflo(v1.y) + bflo(v2.y) + bflo(v3.y);
        a3 += bfhi(v0.y) + bfhi(v1.y) + bfhi(v2.y) + bfhi(v3.y);
        a4 += bflo(v0.z) + bflo(v1.z) + bflo(v2.z) + bflo(v3.z);
        a5 += bfhi(v0.z) + bfhi(v1.z) + bfhi(v2.z) + bfhi(v3.z);
        a6 += bflo(v0.w) + bflo(v1.w) + bflo(v2.w) + bflo(v3.w);
        a7 += bfhi(v0.w) + bfhi(v1.w) + bfhi(v2.w) + bfhi(v3.w);
    }
    if (i + 8 <= cnt) {
        int e0 = csr[start + i + q];
        int e1 = csr[start + i + 4 + q];
        uint4 v0 = *(const uint4*)&p[e0 * 64 + cl * 4];
        uint4 v1 = *(const uint4*)&p[e1 * 64 + cl * 4];
        a0 += bflo(v0.x) + bflo(v1.x); a1 += bfhi(v0.x) + bfhi(v1.x);
        a2 += bflo(v0.y) + bflo(v1.y); a3 += bfhi(v0.y) + bfhi(v1.y);
        a4 += bflo(v0.z) + bflo(v1.z); a5 += bfhi(v0.z) + bfhi(v1.z);
        a6 += bflo(v0.w) + bflo(v1.w); a7 += bfhi(v0.w) + bfhi(v1.w);
        i += 8;
    }
    for (; i < cnt; i += 4) {
        int nbi = i + q;
        if (nbi < cnt) {
            int ia = csr[start + nbi];
            uint4 va = *(const uint4*)&p[ia * 64 + cl * 4];
            a0 += bflo(va.x); a1 += bfhi(va.x);
            a2 += bflo(va.y); a3 += bfhi(va.y);
            a4 += bflo(va.z); a5 += bfhi(va.z);
            a6 += bflo(va.w); a7 += bfhi(va.w);
        }
    }
    a0 += __shfl_xor(a0, 16); a0 += __shfl_xor(a0, 32);
    a1 += __shfl_xor(a1, 16); a1 += __shfl_xor(a1, 32);
    a2 += __shfl_xor(a2, 16); a2 += __shfl_xor(a2, 32);
    a3 += __shfl_xor(a3, 16); a3 += __shfl_xor(a3, 32);
    a4 += __shfl_xor(a4, 16); a4 += __shfl_xor(a4, 32);
    a5 += __shfl_xor(a5, 16); a5 += __shfl_xor(a5, 32);
    a6 += __shfl_xor(a6, 16); a6 += __shfl_xor(a6, 32);
    a7 += __shfl_xor(a7, 16); a7 += __shfl_xor(a7, 32);

    float inv = 1.0f / fmaxf((float)cnt, 1.0f);
    if (q == 0) {
        uint4 o;
        o.x = pkbf(inv * a0, inv * a1);
        o.y = pkbf(inv * a2, inv * a3);
        o.z = pkbf(inv * a4, inv * a5);
        o.w = pkbf(inv * a6, inv * a7);
        *(uint4*)&xagg[gw * 64 + cl * 4] = o;
    }
}

// ---------------- gemm1: h1b = relu([xb | xagg] @ Bt1^T + b1), K=256 ----------------
// 64-row tile, 4 waves x 32 cols; A staged in LDS (swizzled); B direct from global (L2).
__global__ __launch_bounds__(256) void k_gemm1(const unsigned short* __restrict__ xb,
                                               const unsigned short* __restrict__ xagg,
                                               const unsigned short* __restrict__ Bt1,
                                               const float* __restrict__ b1,
                                               unsigned short* __restrict__ h1b, int M) {
    __shared__ unsigned short As[64][256];
    const int m0 = blockIdx.x * 64;
    const int tid = threadIdx.x;
    const int w = tid >> 6;
    const int l = tid & 63;

    const uint4* X4 = (const uint4*)xb;
    const uint4* G4 = (const uint4*)xagg;
    for (int q = tid; q < 2048; q += 256) {
        int row = q >> 5, c = q & 31;
        int gr = m0 + row;
        uint4 v = make_uint4(0, 0, 0, 0);
        if (gr < M) v = (c < 16) ? X4[gr * 16 + c] : G4[gr * 16 + (c - 16)];
        *(uint4*)&As[row][(c ^ (row & 7)) * 8] = v;
    }
    __syncthreads();

    const int fr = l & 15;
    const int kq = l >> 4;
    f32x4 acc[2][4] = {};
#pragma unroll
    for (int kt = 0; kt < 8; ++kt) {
        bf16x8 bfr[2];
#pragma unroll
        for (int ct = 0; ct < 2; ++ct) {
            int nn = w * 32 + ct * 16 + fr;
            bfr[ct] = *(const bf16x8*)&Bt1[nn * 256 + kt * 32 + kq * 8];
        }
        bf16x8 af[4];
#pragma unroll
        for (int rt = 0; rt < 4; ++rt) {
            int row = rt * 16 + fr;
            int c = (kt * 4 + kq) ^ (row & 7);
            af[rt] = *(bf16x8*)&As[row][c * 8];
        }
#pragma unroll
        for (int ct = 0; ct < 2; ++ct)
#pragma unroll
            for (int rt = 0; rt < 4; ++rt)
                acc[ct][rt] = __builtin_amdgcn_mfma_f32_16x16x32_bf16(af[rt], bfr[ct],
                                                                      acc[ct][rt], 0, 0, 0);
    }

#pragma unroll
    for (int ct = 0; ct < 2; ++ct) {
        int col = w * 32 + ct * 16 + fr;
        float bv = b1[col];
#pragma unroll
        for (int rt = 0; rt < 4; ++rt) {
#pragma unroll
            for (int j = 0; j < 4; ++j) {
                int row = m0 + rt * 16 + (l >> 4) * 4 + j;
                if (row < M) h1b[row * 128 + col] = f2bf(fmaxf(acc[ct][rt][j] + bv, 0.f));
            }
        }
    }
}

// ---------------- gemm2: [out | p2] = h1b @ Bt2^T (+b2 on out), K=128 ---------------
__global__ __launch_bounds__(256) void k_gemm2(const unsigned short* __restrict__ h1b,
                                               const unsigned short* __restrict__ Bt2,
                                               const float* __restrict__ b2,
                                               float* __restrict__ out,
                                               unsigned short* __restrict__ p2, int M) {
    __shared__ unsigned short As[64][128];
    const int m0 = blockIdx.x * 64;
    const int tid = threadIdx.x;
    const int w = tid >> 6;
    const int l = tid & 63;

    const uint4* A4 = (const uint4*)h1b;
    for (int q = tid; q < 1024; q += 256) {
        int row = q >> 4, c = q & 15;
        int gr = m0 + row;
        uint4 v = make_uint4(0, 0, 0, 0);
        if (gr < M) v = A4[gr * 16 + c];
        *(uint4*)&As[row][(c ^ (row & 7)) * 8] = v;
    }
    __syncthreads();

    const int fr = l & 15;
    const int kq = l >> 4;
    f32x4 acc[2][4] = {};
#pragma unroll
    for (int kt = 0; kt < 4; ++kt) {
        bf16x8 bfr[2];
#pragma unroll
        for (int ct = 0; ct < 2; ++ct) {
            int nn = w * 32 + ct * 16 + fr;
            bfr[ct] = *(const bf16x8*)&Bt2[nn * 128 + kt * 32 + kq * 8];
        }
        bf16x8 af[4];
#pragma unroll
        for (int rt = 0; rt < 4; ++rt) {
            int row = rt * 16 + fr;
            int c = (kt * 4 + kq) ^ (row & 7);
            af[rt] = *(bf16x8*)&As[row][c * 8];
        }
#pragma unroll
        for (int ct = 0; ct < 2; ++ct)
#pragma unroll
            for (int rt = 0; rt < 4; ++rt)
                acc[ct][rt] = __builtin_amdgcn_mfma_f32_16x16x32_bf16(af[rt], bfr[ct],
                                                                      acc[ct][rt], 0, 0, 0);
    }

#pragma unroll
    for (int ct = 0; ct < 2; ++ct) {
        int col = w * 32 + ct * 16 + fr;
        bool isS = col < 64;  // wave-quarter uniform per 16-col tile
        float bv = isS ? b2[col] : 0.f;
#pragma unroll
        for (int rt = 0; rt < 4; ++rt) {
#pragma unroll
            for (int j = 0; j < 4; ++j) {
                int row = m0 + rt * 16 + (l >> 4) * 4 + j;
                if (row < M) {
                    float v = acc[ct][rt][j];
                    if (isS) out[row * 64 + col] = v + bv;
                    else p2[row * 64 + (col - 64)] = f2bf(v);
                }
            }
        }
    }
}

// ---------------- layer-2 aggregation: out += mean_neigh(p2) (64 ch bf16) ----------
// 8 groups of 8 lanes; each group gathers one 128B row via uint4 (8 rows/instr).
__global__ __launch_bounds__(256) void k_agg2_add(const unsigned int* __restrict__ p,
                                                  float* __restrict__ out,
                                                  const int* __restrict__ row_start,
                                                  const int* __restrict__ deg,
                                                  const int* __restrict__ csr, int n) {
    int gw = (blockIdx.x * 256 + threadIdx.x) >> 6;
    int lane = threadIdx.x & 63;
    if (gw >= n) return;
    int start = row_start[gw];
    int cnt = deg[gw];
    const int g = lane >> 3;
    const int cl = lane & 7;
    float a0 = 0.f, a1 = 0.f, a2 = 0.f, a3 = 0.f, a4 = 0.f, a5 = 0.f, a6 = 0.f, a7 = 0.f;
    int i = 0;
    for (; i + 16 <= cnt; i += 16) {
        int e0 = csr[start + i + g];
        int e1 = csr[start + i + 8 + g];
        uint4 v0 = *(const uint4*)&p[e0 * 32 + cl * 4];
        uint4 v1 = *(const uint4*)&p[e1 * 32 + cl * 4];
        a0 += bflo(v0.x) + bflo(v1.x); a1 += bfhi(v0.x) + bfhi(v1.x);
        a2 += bflo(v0.y) + bflo(v1.y); a3 += bfhi(v0.y) + bfhi(v1.y);
        a4 += bflo(v0.z) + bflo(v1.z); a5 += bfhi(v0.z) + bfhi(v1.z);
        a6 += bflo(v0.w) + bflo(v1.w); a7 += bfhi(v0.w) + bfhi(v1.w);
    }
    for (; i < cnt; i += 8) {
        int nbi = i + g;
        if (nbi < cnt) {
            int ia = csr[start + nbi];
            uint4 va = *(const uint4*)&p[ia * 32 + cl * 4];
            a0 += bflo(va.x); a1 += bfhi(va.x);
            a2 += bflo(va.y); a3 += bfhi(va.y);
            a4 += bflo(va.z); a5 += bfhi(va.z);
            a6 += bflo(va.w); a7 += bfhi(va.w);
        }
    }
    a0 += __shfl_xor(a0, 8); a0 += __shfl_xor(a0, 16); a0 += __shfl_xor(a0, 32);
    a1 += __shfl_xor(a1, 8); a1 += __shfl_xor(a1, 16); a1 += __shfl_xor(a1, 32);
    a2 += __shfl_xor(a2, 8); a2 += __shfl_xor(a2, 16); a2 += __shfl_xor(a2, 32);
    a3 += __shfl_xor(a3, 8); a3 += __shfl_xor(a3, 16); a3 += __shfl_xor(a3, 32);
    a4 += __shfl_xor(a4, 8); a4 += __shfl_xor(a4, 16); a4 += __shfl_xor(a4, 32);
    a5 += __shfl_xor(a5, 8); a5 += __shfl_xor(a5, 16); a5 += __shfl_xor(a5, 32);
    a6 += __shfl_xor(a6, 8); a6 += __shfl_xor(a6, 16); a6 += __shfl_xor(a6, 32);
    a7 += __shfl_xor(a7, 8); a7 += __shfl_xor(a7, 16); a7 += __shfl_xor(a7, 32);
    float inv = 1.0f / fmaxf((float)cnt, 1.0f);
    if (g == 0) {
        float4 oa = *(const float4*)&out[gw * 64 + cl * 8];
        float4 ob = *(const float4*)&out[gw * 64 + cl * 8 + 4];
        oa.x += inv * a0; oa.y += inv * a1; oa.z += inv * a2; oa.w += inv * a3;
        ob.x += inv * a4; ob.y += inv * a5; ob.z += inv * a6; ob.w += inv * a7;
        *(float4*)&out[gw * 64 + cl * 8] = oa;
        *(float4*)&out[gw * 64 + cl * 8 + 4] = ob;
    }
}

extern "C" void kernel_launch(void* const* d_in, const int* in_sizes, int n_in,
                              void* d_out, int out_size, void* d_ws, size_t ws_size,
                              hipStream_t stream) {
    const float* x   = (const float*)d_in[0];
    const int*   src = (const int*)d_in[1];
    const int*   dst = (const int*)d_in[2];
    const float* Ws1 = (const float*)d_in[3];
    const float* Wn1 = (const float*)d_in[4];
    const float* b1  = (const float*)d_in[5];
    const float* Ws2 = (const float*)d_in[6];
    const float* Wn2 = (const float*)d_in[7];
    const float* b2  = (const float*)d_in[8];
    float* out = (float*)d_out;
    const int N = in_sizes[0] / N_CH;  // 50000
    const int E = in_sizes[1];         // 800000

    // workspace layout (256B-aligned). rank dead after fill_csr; xagg aliases it.
    char* ws = (char*)d_ws;
    int* deg       = (int*)(ws + 0);          // N ints -> 200704
    int* row_start = (int*)(ws + 200704);     // N ints -> 401408
    int* bsum      = (int*)(ws + 401408);     // <=256 ints -> 402432
    int* csr_src   = (int*)(ws + 402432);     // E ints -> 3602432 (persists)
    int* rank      = (int*)(ws + 3602432);    // E ints (dead after fill)
    unsigned short* xagg = (unsigned short*)(ws + 3602432);   // bf16 [N][128] -> 16402432 (aliases rank)
    unsigned short* xb   = (unsigned short*)(ws + 16402432);  // bf16 [N][128] -> 29202432
    unsigned short* h1b  = (unsigned short*)(ws + 29202432);  // bf16 [N][128] -> 42002432
    unsigned short* p2   = (unsigned short*)(ws + 42002432);  // bf16 [N][64]  -> 48402432
    unsigned short* Bt1  = (unsigned short*)(ws + 48402432);  // [128][256] 64KB -> 48467968
    unsigned short* Bt2  = (unsigned short*)(ws + 48467968);  // [128][128] 32KB -> 48500736

    const int eb = (E + 255) / 256;   // 3125
    const int nb = (N + 255) / 256;   // 196 <= 256: single-block scan ok
    const int ndeg4 = (N + 3) / 4;    // 12500
    const int nxq = N * 16;           // 800000 uint4 outputs for xcast

    k_init<<<241 + (nxq + 255) / 256, 256, 0, stream>>>(x, Ws1, Wn1, Ws2, Wn2, deg, Bt1, Bt2,
                                                        (uint4*)xb, ndeg4, nxq);
    k_deg_rank<<<eb, 256, 0, stream>>>(dst, deg, rank, E);
    k_block_reduce<<<nb, 256, 0, stream>>>(deg, bsum, N);
    k_scan_bsum<<<1, 256, 0, stream>>>(bsum, nb);
    k_scan_final<<<nb, 256, 0, stream>>>(deg, bsum, row_start, N);
    k_fill_csr<<<eb, 256, 0, stream>>>(src, dst, rank, row_start, csr_src, E);

    const int gb = (N + 63) / 64;  // 782
    k_aggx<<<(N + 3) / 4, 256, 0, stream>>>((const unsigned int*)xb, (unsigned int*)xagg,
                                            row_start, deg, csr_src, N);
    k_gemm1<<<gb, 256, 0, stream>>>(xb, xagg, Bt1, b1, h1b, N);
    k_gemm2<<<gb, 256, 0, stream>>>(h1b, Bt2, b2, out, p2, N);
    k_agg2_add<<<(N + 3) / 4, 256, 0, stream>>>((const unsigned int*)p2, out, row_start, deg,
                                                csr_src, N);
}